// Round 1
// baseline (126.620 us; speedup 1.0000x reference)
//
#include <hip/hip_runtime.h>
#include <hip/hip_bf16.h>

using bf16 = __hip_bfloat16;
typedef __attribute__((ext_vector_type(8))) short frag_ab;   // 8 bf16
typedef __attribute__((ext_vector_type(4))) float frag_cd;   // 4 fp32

constexpr float TEMP   = 0.07f;
constexpr float INVT   = 1.0f / TEMP;                 // fixed logsumexp shift
constexpr float THRESH = 0.1f;
constexpr float EPS    = 1e-8f;
constexpr float LOG2E  = 1.4426950408889634f;
constexpr float C1     = LOG2E / TEMP;                // exp((s-1)/T) = exp2(s*C1 - C1)

constexpr int D      = 128;
constexpr int SPLITS = 16;    // column splits

__device__ __forceinline__ frag_cd mfma16(frag_ab a, frag_ab b, frag_cd c) {
    return __builtin_amdgcn_mfma_f32_16x16x32_bf16(a, b, c, 0, 0, 0);
}

// ------- kernel 1: row-normalize -> bf16, diagonal dot, zero-init reduction cells -------
__global__ __launch_bounds__(256) void k1_normalize(
    const float* __restrict__ f, bf16* __restrict__ fn,
    float* __restrict__ diag, float* __restrict__ acc,
    unsigned* __restrict__ counter, int n)
{
    if (blockIdx.x == 0 && threadIdx.x == 0) { acc[0] = 0.f; counter[0] = 0u; }
    const int row  = blockIdx.x * 4 + (threadIdx.x >> 6);
    const int lane = threadIdx.x & 63;
    float2 v = ((const float2*)(f + (size_t)row * D))[lane];
    float ss = v.x * v.x + v.y * v.y;
    #pragma unroll
    for (int m = 32; m >= 1; m >>= 1) ss += __shfl_xor(ss, m, 64);
    const float inv = 1.0f / fmaxf(sqrtf(ss), EPS);
    __hip_bfloat162 o;
    o.x = __float2bfloat16(v.x * inv);
    o.y = __float2bfloat16(v.y * inv);
    ((__hip_bfloat162*)(fn + (size_t)row * D))[lane] = o;
    // diagonal raw dot of the bf16-rounded row (matches MFMA s_ii to ~1e-6)
    const float a = __bfloat162float(o.x), b = __bfloat162float(o.y);
    float p = a * a + b * b;
    #pragma unroll
    for (int m = 32; m >= 1; m >>= 1) p += __shfl_xor(p, m, 64);
    if (lane == 0) diag[row] = p;
}

// ---------------- kernel 2: fused sim + masked reductions (no LDS, no barriers) ----------------
// fn is 2 MB -> fully L2-resident per XCD. Stage NOTHING: each 1-wave block owns 32 rows
// (2 x 16-row A-fragment sets) and streams its 512-col strip as 16-col groups of
// B-fragments read straight from L2 into registers, depth-1 prefetched (next group's
// 4x16B loads + label issue before current group's 8 MFMA + epilogue -> ~250cy L2
// latency hides under ~350cy compute). Zero __syncthreads, LDS=0, 4096 independent
// waves, <=128 VGPR target -> 4 waves/SIMD.
__global__ __launch_bounds__(64, 4) void k2_main(
    const bf16* __restrict__ fn, const float* __restrict__ lab,
    float* __restrict__ se_p, float* __restrict__ sp_p,
    float* __restrict__ cnt_p, int n)
{
    const int lane = threadIdx.x & 63;
    const int quad = lane >> 4;
    const int l15  = lane & 15;

    const int cps      = n / SPLITS;        // 512
    const int cbase    = blockIdx.y * cps;
    const int row_base = blockIdx.x * 32;

    // A fragments: set s covers rows row_base + s*16 + l15, k = kb*32 + quad*8 + j
    frag_ab afr[2][4];
    #pragma unroll
    for (int s = 0; s < 2; ++s) {
        const bf16* ap = fn + (size_t)(row_base + s * 16 + l15) * D + quad * 8;
        #pragma unroll
        for (int kb = 0; kb < 4; ++kb) afr[s][kb] = *(const frag_ab*)(ap + kb * 32);
    }
    float li[2][4];
    #pragma unroll
    for (int s = 0; s < 2; ++s)
        #pragma unroll
        for (int r = 0; r < 4; ++r)
            li[s][r] = lab[row_base + s * 16 + quad * 4 + r];

    float se[2][4] = {}, sp[2][4] = {}, cnt[2][4] = {};

    const int ngroups = cps / 16;                       // 32
    const int g0 = (blockIdx.x + blockIdx.y) & (ngroups - 1);   // convoy stagger

    // B-fragment group load: column c = cbase + g*16 + l15, same address form as A.
    frag_ab bcur[4];
    float   ljc;
    {
        const int c = cbase + g0 * 16 + l15;
        const bf16* bp = fn + (size_t)c * D + quad * 8;
        #pragma unroll
        for (int kb = 0; kb < 4; ++kb) bcur[kb] = *(const frag_ab*)(bp + kb * 32);
        ljc = lab[c];
    }

    auto compute = [&](const frag_ab (&bb)[4], const float lj) {
        frag_cd a0 = {0.f, 0.f, 0.f, 0.f}, a1 = {0.f, 0.f, 0.f, 0.f};
        #pragma unroll
        for (int kb = 0; kb < 4; ++kb) {
            a0 = mfma16(afr[0][kb], bb[kb], a0);
            a1 = mfma16(afr[1][kb], bb[kb], a1);
        }
        #pragma unroll
        for (int s = 0; s < 2; ++s) {
            const frag_cd& acc = s ? a1 : a0;
            #pragma unroll
            for (int r = 0; r < 4; ++r) {
                const float sv = acc[r];                      // raw dot (cosine)
                const float e  = __builtin_amdgcn_exp2f(__builtin_fmaf(sv, C1, -C1));
                const float pm = (fabsf(li[s][r] - lj) < THRESH) ? 1.0f : 0.0f;
                se[s][r]  += e;
                sp[s][r]   = __builtin_fmaf(pm, sv, sp[s][r]); // raw dots; 1/T in k3
                cnt[s][r] += pm;
            }
        }
    };

    for (int t = 0; t < ngroups - 1; ++t) {
        // issue next group's loads NOW — in flight across compute on the current group
        const int gn = (g0 + t + 1) & (ngroups - 1);
        const int c  = cbase + gn * 16 + l15;
        const bf16* bp = fn + (size_t)c * D + quad * 8;
        frag_ab bnxt[4];
        #pragma unroll
        for (int kb = 0; kb < 4; ++kb) bnxt[kb] = *(const frag_ab*)(bp + kb * 32);
        const float ljn = lab[c];

        compute(bcur, ljc);

        #pragma unroll
        for (int kb = 0; kb < 4; ++kb) bcur[kb] = bnxt[kb];
        ljc = ljn;
    }
    compute(bcur, ljc);   // epilogue group

    // reduce across the 16 lanes of each quad-group (same rows, cols mod 16)
    #pragma unroll
    for (int s = 0; s < 2; ++s)
        #pragma unroll
        for (int r = 0; r < 4; ++r) {
            #pragma unroll
            for (int m = 1; m < 16; m <<= 1) {
                se[s][r]  += __shfl_xor(se[s][r],  m, 64);
                sp[s][r]  += __shfl_xor(sp[s][r],  m, 64);
                cnt[s][r] += __shfl_xor(cnt[s][r], m, 64);
            }
        }
    if (l15 == 0) {
        #pragma unroll
        for (int s = 0; s < 2; ++s)
            #pragma unroll
            for (int r = 0; r < 4; ++r) {
                const int i = row_base + s * 16 + quad * 4 + r;
                se_p[(size_t)blockIdx.y * n + i]  = se[s][r];
                sp_p[(size_t)blockIdx.y * n + i]  = sp[s][r];
                cnt_p[(size_t)blockIdx.y * n + i] = cnt[s][r];
            }
    }
}

// ------- kernel 3: per-row finalize + grid reduction (last-block pattern) -------
__global__ __launch_bounds__(256) void k3_finalize(
    const float* __restrict__ diag, const float* __restrict__ se_p,
    const float* __restrict__ sp_p, const float* __restrict__ cnt_p,
    float* __restrict__ acc, unsigned* __restrict__ counter,
    float* __restrict__ out, int n)
{
    const int row = blockIdx.x * 256 + threadIdx.x;
    float se = 0.f, sp = 0.f, cnt = 0.f;
    #pragma unroll
    for (int s = 0; s < SPLITS; ++s) {
        se  += se_p[(size_t)s * n + row];
        sp  += sp_p[(size_t)s * n + row];
        cnt += cnt_p[(size_t)s * n + row];
    }
    const float s_ii = diag[row];
    se  -= __builtin_amdgcn_exp2f(__builtin_fmaf(s_ii, C1, -C1));
    sp  -= s_ii;
    cnt -= 1.0f;
    float loss = INVT + __logf(se) - (sp * INVT) / fmaxf(cnt, 1.0f);

    // block reduce
    #pragma unroll
    for (int m = 32; m >= 1; m >>= 1) loss += __shfl_xor(loss, m, 64);
    __shared__ float wsum[4];
    if ((threadIdx.x & 63) == 0) wsum[threadIdx.x >> 6] = loss;
    __syncthreads();
    if (threadIdx.x == 0) {
        const float bs = wsum[0] + wsum[1] + wsum[2] + wsum[3];
        atomicAdd(acc, bs);
        __threadfence();
        const unsigned old = atomicAdd(counter, 1u);
        if (old == gridDim.x - 1) {
            const float total = atomicAdd(acc, 0.0f);  // atomic load, same-address order
            out[0] = total / (float)n;
        }
    }
}

extern "C" void kernel_launch(void* const* d_in, const int* in_sizes, int n_in,
                              void* d_out, int out_size, void* d_ws, size_t ws_size,
                              hipStream_t stream) {
    const float* feat = (const float*)d_in[0];
    const float* lab  = (const float*)d_in[1];
    const int n = in_sizes[1];              // 8192
    float* out = (float*)d_out;

    // ws: fn (n*D bf16 = 2MB) | diag | se_p | sp_p | cnt_p (each SPLITS*n f32) | acc | counter
    char* ws = (char*)d_ws;
    bf16* fn = (bf16*)ws;
    size_t off = (size_t)n * D * sizeof(bf16);
    float* diag  = (float*)(ws + off); off += (size_t)n * sizeof(float);
    float* se_p  = (float*)(ws + off); off += (size_t)SPLITS * n * sizeof(float);
    float* sp_p  = (float*)(ws + off); off += (size_t)SPLITS * n * sizeof(float);
    float* cnt_p = (float*)(ws + off); off += (size_t)SPLITS * n * sizeof(float);
    float* acc   = (float*)(ws + off); off += sizeof(float);
    unsigned* counter = (unsigned*)(ws + off);

    k1_normalize<<<n / 4, 256, 0, stream>>>(feat, fn, diag, acc, counter, n);
    dim3 g2(n / 32, SPLITS);
    k2_main<<<g2, 64, 0, stream>>>(fn, lab, se_p, sp_p, cnt_p, n);
    k3_finalize<<<n / 256, 256, 0, stream>>>(diag, se_p, sp_p, cnt_p, acc, counter, out, n);
}